// Round 2
// baseline (266.928 us; speedup 1.0000x reference)
//
#include <hip/hip_runtime.h>
#include <cstdint>
#include <cstddef>
#include <math.h>

typedef _Float16 half8 __attribute__((ext_vector_type(8)));
typedef _Float16 half4 __attribute__((ext_vector_type(4)));
typedef float f32x4 __attribute__((ext_vector_type(4)));

#define NB  2
#define NT  2048
#define NC  1024
#define NH  16
#define ND  64

__device__ __forceinline__ void gload_lds16(const _Float16* g, _Float16* l) {
  __builtin_amdgcn_global_load_lds((const __attribute__((address_space(1))) void*)g,
                                   (__attribute__((address_space(3))) void*)l, 16, 0, 0);
}

// ---------------- convert x -> fp16 ----------------
__global__ void k_cvt_x(const float* __restrict__ x, _Float16* __restrict__ xh) {
  const int n4 = (4096 * 1024) / 4;
  int i = blockIdx.x * 256 + threadIdx.x;
  for (; i < n4; i += 2048 * 256) {
    float4 v = ((const float4*)x)[i];
    half4 h = { (_Float16)v.x, (_Float16)v.y, (_Float16)v.z, (_Float16)v.w };
    ((half4*)xh)[i] = h;
  }
}

// ------------- transpose+convert W (1024x1024) -> WT[n][k] fp16 -------------
__global__ void k_tw(const float* __restrict__ W0, const float* __restrict__ W1,
                     const float* __restrict__ W2, const float* __restrict__ W3,
                     _Float16* __restrict__ WT) {
  const float* W = (blockIdx.z == 0) ? W0 : (blockIdx.z == 1) ? W1 : (blockIdx.z == 2) ? W2 : W3;
  _Float16* out = WT + ((size_t)blockIdx.z << 20);
  __shared__ float t[32][33];
  const int x0 = blockIdx.x * 32;  // n
  const int y0 = blockIdx.y * 32;  // k
  const int tx = threadIdx.x, ty = threadIdx.y;  // (32,8)
#pragma unroll
  for (int r = 0; r < 4; ++r)
    t[ty + 8 * r][tx] = W[(size_t)(y0 + ty + 8 * r) * 1024 + x0 + tx];
  __syncthreads();
#pragma unroll
  for (int r = 0; r < 4; ++r)
    out[(size_t)(x0 + ty + 8 * r) * 1024 + y0 + tx] = (_Float16)t[tx][ty + 8 * r];
}

// ---------------- shared GEMM mainloop: C(128x128) = A(128xK) * B^T(128xK) ----------------
__device__ __forceinline__ void gemm_mainloop(const _Float16* __restrict__ A,
                                              const _Float16* __restrict__ Bmat,
                                              int m0, int n0,
                                              _Float16* As, _Float16* Bs,
                                              f32x4 acc[4][4]) {
  const int tid = threadIdx.x;
  const int lane = tid & 63;
  const int wid = tid >> 6;
  const int wm = wid >> 1, wn = wid & 1;
  const int c16 = lane & 15, rg = lane >> 4;

  for (int k0 = 0; k0 < 1024; k0 += 64) {
    __syncthreads();
#pragma unroll
    for (int i = 0; i < 4; ++i) {
      int e = (i * 256 + tid) * 8;       // element index within 128x64 tile
      int row = e >> 6;                  // 0..127
      int chunk = (e & 63) >> 3;         // 0..7 (16B chunk)
      int scol = ((chunk ^ (row & 7)) << 3);  // source-side swizzle (involution)
      gload_lds16(A + (size_t)(m0 + row) * 1024 + k0 + scol,
                  As + (size_t)(i * 256 + (wid << 6)) * 8);
      gload_lds16(Bmat + (size_t)(n0 + row) * 1024 + k0 + scol,
                  Bs + (size_t)(i * 256 + (wid << 6)) * 8);
    }
    __syncthreads();
#pragma unroll
    for (int kk = 0; kk < 2; ++kk) {
      half8 af[4], bfr[4];
#pragma unroll
      for (int mi = 0; mi < 4; ++mi) {
        int row = (wm << 6) + (mi << 4) + c16;
        int chunk = (kk << 2) + rg;
        af[mi] = *(const half8*)&As[(row << 6) + ((chunk ^ (row & 7)) << 3)];
      }
#pragma unroll
      for (int ni = 0; ni < 4; ++ni) {
        int row = (wn << 6) + (ni << 4) + c16;
        int chunk = (kk << 2) + rg;
        bfr[ni] = *(const half8*)&Bs[(row << 6) + ((chunk ^ (row & 7)) << 3)];
      }
#pragma unroll
      for (int mi = 0; mi < 4; ++mi)
#pragma unroll
        for (int ni = 0; ni < 4; ++ni)
          acc[mi][ni] = __builtin_amdgcn_mfma_f32_16x16x32_f16(af[mi], bfr[ni], acc[mi][ni], 0, 0, 0);
    }
  }
}

// ---------------- QKV GEMM + bias + RoPE + scatter to (b,h,t,d) ----------------
__global__ __launch_bounds__(256, 2) void k_qkv(const _Float16* __restrict__ xh,
                                                const _Float16* __restrict__ WT,
                                                const float* __restrict__ bq,
                                                const float* __restrict__ bk,
                                                const float* __restrict__ bv,
                                                _Float16* __restrict__ Qh,
                                                _Float16* __restrict__ Kh,
                                                _Float16* __restrict__ Vh) {
  __shared__ __align__(16) _Float16 As[128 * 64];
  __shared__ __align__(16) _Float16 Bs[128 * 64];
  f32x4 acc[4][4];
#pragma unroll
  for (int i = 0; i < 4; ++i)
#pragma unroll
    for (int j = 0; j < 4; ++j) acc[i][j] = (f32x4){0.f, 0.f, 0.f, 0.f};

  const int m0 = blockIdx.y * 128;
  const int ng = blockIdx.x * 128;   // 0..3071
  const int p = ng >> 10;            // 0=q,1=k,2=v
  const int n0 = ng & 1023;
  gemm_mainloop(xh, WT + ((size_t)p << 20), m0, n0, As, Bs, acc);

  const int tid = threadIdx.x, lane = tid & 63, wid = tid >> 6;
  const int wm = wid >> 1, wn = wid & 1, c16 = lane & 15, rg = lane >> 4;
  const float* bias = (p == 0) ? bq : (p == 1) ? bk : bv;
  _Float16* Out = (p == 0) ? Qh : (p == 1) ? Kh : Vh;
  const int nw = n0 + (wn << 6);
  const int head = nw >> 6;          // wave's 64-col strip is exactly one head
  float bi[4];
#pragma unroll
  for (int ni = 0; ni < 4; ++ni) bi[ni] = bias[nw + (ni << 4) + c16];
  // inv_freq[c16] = 10000^(-c16/16) = 2^(-c16 * log2(10000)/16)  (accurate exp2)
  const float invf = exp2f((float)c16 * -0.8304820237218405f);

#pragma unroll
  for (int mi = 0; mi < 4; ++mi) {
#pragma unroll
    for (int r = 0; r < 4; ++r) {
      int m = m0 + (wm << 6) + (mi << 4) + (rg << 2) + r;
      int b = m >> 11, t = m & 2047;
      float v0 = acc[mi][0][r] + bi[0];
      float v1 = acc[mi][1][r] + bi[1];
      float v2 = acc[mi][2][r] + bi[2];
      float v3 = acc[mi][3][r] + bi[3];
      if (p < 2) {  // RoPE on d<32: pair (d, d+16)
        float th = (float)t * invf;
        float sn, cs;
        sincosf(th, &sn, &cs);   // libm-accurate: theta reaches 2047 rad, needs
                                 // full Payne-Hanek reduction (native v_sin fails here)
        float nx = v0 * cs - v1 * sn;
        v1 = v1 * cs + v0 * sn;
        v0 = nx;
      }
      size_t base = ((size_t)(b * NH + head) * NT + t) * ND;
      Out[base + 0 + c16] = (_Float16)v0;
      Out[base + 16 + c16] = (_Float16)v1;
      Out[base + 32 + c16] = (_Float16)v2;
      Out[base + 48 + c16] = (_Float16)v3;
    }
  }
}

// ---------------- flash attention: block = (bh, 64 q-rows), 4 waves x 16 rows ----------------
__global__ __launch_bounds__(256) void k_attn(const _Float16* __restrict__ Qh,
                                              const _Float16* __restrict__ Kh,
                                              const _Float16* __restrict__ Vh,
                                              _Float16* __restrict__ Oh) {
  const int bh = blockIdx.y;
  const int qi = gridDim.x - 1 - blockIdx.x;  // big tiles dispatch first (tail balance)
  const int q0 = qi * 64;
  const int tid = threadIdx.x, lane = tid & 63, wid = tid >> 6;
  const int c16 = lane & 15, rg = lane >> 4;
  const size_t hb = (size_t)bh * NT * ND;

  __shared__ __align__(16) _Float16 Vt[64][40];      // [d][kv] transposed V tile
  __shared__ __align__(16) _Float16 Pl[4][16][40];   // per-wave P [q_local][kv]

  const int qrow = q0 + (wid << 4) + c16;
  half8 qf0 = *(const half8*)&Qh[hb + (size_t)qrow * ND + (rg << 3)];
  half8 qf1 = *(const half8*)&Qh[hb + (size_t)qrow * ND + 32 + (rg << 3)];

  f32x4 oacc[4];
#pragma unroll
  for (int i = 0; i < 4; ++i) oacc[i] = (f32x4){0.f, 0.f, 0.f, 0.f};
  float mrow[4] = {-INFINITY, -INFINITY, -INFINITY, -INFINITY};
  float lrow[4] = {0.f, 0.f, 0.f, 0.f};

  const int ktend = q0 + 64;
  for (int kt = 0; kt < ktend; kt += 32) {
    __syncthreads();
    {  // stage V tile transposed: V[kt+r][c] -> Vt[c][r]
      int r = tid >> 3;
      int c0 = (tid & 7) << 3;
      half8 vv = *(const half8*)&Vh[hb + (size_t)(kt + r) * ND + c0];
#pragma unroll
      for (int j = 0; j < 8; ++j) Vt[c0 + j][r] = vv[j];
    }
    __syncthreads();

    // S = Q(16x64) * K^T(64x32) ; K read direct from global (L2-resident)
    f32x4 s[2];
#pragma unroll
    for (int ni = 0; ni < 2; ++ni) {
      const size_t krow = hb + (size_t)(kt + (ni << 4) + c16) * ND;
      half8 kf0 = *(const half8*)&Kh[krow + (rg << 3)];
      half8 kf1 = *(const half8*)&Kh[krow + 32 + (rg << 3)];
      f32x4 z = (f32x4){0.f, 0.f, 0.f, 0.f};
      z = __builtin_amdgcn_mfma_f32_16x16x32_f16(qf0, kf0, z, 0, 0, 0);
      s[ni] = __builtin_amdgcn_mfma_f32_16x16x32_f16(qf1, kf1, z, 0, 0, 0);
    }

    // online softmax (row stats per lane: rows rg*4+r, cols = c16 across 16 lanes)
#pragma unroll
    for (int r = 0; r < 4; ++r) {
      int q = q0 + (wid << 4) + (rg << 2) + r;
      float sv0 = s[0][r] * 0.125f;
      float sv1 = s[1][r] * 0.125f;
      if (kt + c16 > q) sv0 = -INFINITY;
      if (kt + 16 + c16 > q) sv1 = -INFINITY;
      float mt = fmaxf(sv0, sv1);
#pragma unroll
      for (int d = 1; d < 16; d <<= 1) mt = fmaxf(mt, __shfl_xor(mt, d));
      float mnew = fmaxf(mrow[r], mt);
      float corr = __expf(mrow[r] - mnew);   // mrow=-inf -> 0 (first tile), ok
      float p0 = __expf(sv0 - mnew);
      float p1 = __expf(sv1 - mnew);
      float ps = p0 + p1;
#pragma unroll
      for (int d = 1; d < 16; d <<= 1) ps += __shfl_xor(ps, d);
      lrow[r] = lrow[r] * corr + ps;
      mrow[r] = mnew;
#pragma unroll
      for (int ni = 0; ni < 4; ++ni) oacc[ni][r] *= corr;
      Pl[wid][(rg << 2) + r][c16] = (_Float16)p0;
      Pl[wid][(rg << 2) + r][16 + c16] = (_Float16)p1;
    }

    // PV: out(16x64) += P(16x32) * V(32x64)
    half8 pa = *(const half8*)&Pl[wid][c16][rg << 3];
#pragma unroll
    for (int ni = 0; ni < 4; ++ni) {
      half8 vf = *(const half8*)&Vt[(ni << 4) + c16][rg << 3];
      oacc[ni] = __builtin_amdgcn_mfma_f32_16x16x32_f16(pa, vf, oacc[ni], 0, 0, 0);
    }
  }

  // epilogue: normalize, store O as [b*T+t][h*64+d] fp16
  const int b = bh >> 4, h = bh & 15;
  float il[4];
#pragma unroll
  for (int r = 0; r < 4; ++r) il[r] = 1.f / lrow[r];
#pragma unroll
  for (int r = 0; r < 4; ++r) {
    int q = q0 + (wid << 4) + (rg << 2) + r;
    size_t base = ((size_t)b * NT + q) * NC + h * ND;
#pragma unroll
    for (int ni = 0; ni < 4; ++ni)
      Oh[base + (ni << 4) + c16] = (_Float16)(oacc[ni][r] * il[r]);
  }
}

// ---------------- output projection GEMM (fp32 out + bias) ----------------
__global__ __launch_bounds__(256, 2) void k_out(const _Float16* __restrict__ Oh,
                                                const _Float16* __restrict__ WoT,
                                                const float* __restrict__ bo,
                                                float* __restrict__ out) {
  __shared__ __align__(16) _Float16 As[128 * 64];
  __shared__ __align__(16) _Float16 Bs[128 * 64];
  f32x4 acc[4][4];
#pragma unroll
  for (int i = 0; i < 4; ++i)
#pragma unroll
    for (int j = 0; j < 4; ++j) acc[i][j] = (f32x4){0.f, 0.f, 0.f, 0.f};

  const int m0 = blockIdx.y * 128;
  const int n0 = blockIdx.x * 128;
  gemm_mainloop(Oh, WoT, m0, n0, As, Bs, acc);

  const int tid = threadIdx.x, lane = tid & 63, wid = tid >> 6;
  const int wm = wid >> 1, wn = wid & 1, c16 = lane & 15, rg = lane >> 4;
  float bi[4];
#pragma unroll
  for (int ni = 0; ni < 4; ++ni) bi[ni] = bo[n0 + (wn << 6) + (ni << 4) + c16];
#pragma unroll
  for (int mi = 0; mi < 4; ++mi) {
#pragma unroll
    for (int r = 0; r < 4; ++r) {
      int m = m0 + (wm << 6) + (mi << 4) + (rg << 2) + r;
#pragma unroll
      for (int ni = 0; ni < 4; ++ni) {
        int n = n0 + (wn << 6) + (ni << 4) + c16;
        out[(size_t)m * NC + n] = acc[mi][ni][r] + bi[ni];
      }
    }
  }
}

extern "C" void kernel_launch(void* const* d_in, const int* in_sizes, int n_in,
                              void* d_out, int out_size, void* d_ws, size_t ws_size,
                              hipStream_t stream) {
  const float* x  = (const float*)d_in[0];
  const float* Wq = (const float*)d_in[1];
  const float* bq = (const float*)d_in[2];
  const float* Wk = (const float*)d_in[3];
  const float* bk = (const float*)d_in[4];
  const float* Wv = (const float*)d_in[5];
  const float* bv = (const float*)d_in[6];
  const float* Wo = (const float*)d_in[7];
  const float* bo = (const float*)d_in[8];
  float* out = (float*)d_out;

  char* ws = (char*)d_ws;
  _Float16* xh = (_Float16*)ws;                       // 8 MB  [4096][1024]
  _Float16* WT = (_Float16*)(ws + (8ull << 20));      // 8 MB  [4][1024][1024] n-major
  _Float16* Qh = (_Float16*)(ws + (16ull << 20));     // 8 MB  [32][2048][64]
  _Float16* Kh = (_Float16*)(ws + (24ull << 20));     // 8 MB
  _Float16* Vh = (_Float16*)(ws + (32ull << 20));     // 8 MB
  _Float16* Oh = (_Float16*)(ws + (40ull << 20));     // 8 MB  [4096][1024]

  k_cvt_x<<<2048, 256, 0, stream>>>(x, xh);
  k_tw<<<dim3(32, 32, 4), dim3(32, 8), 0, stream>>>(Wq, Wk, Wv, Wo, WT);
  k_qkv<<<dim3(24, 32), 256, 0, stream>>>(xh, WT, bq, bk, bv, Qh, Kh, Vh);
  k_attn<<<dim3(32, 32), 256, 0, stream>>>(Qh, Kh, Vh, Oh);
  k_out<<<dim3(8, 32), 256, 0, stream>>>(Oh, WT + (3ull << 20), bo, out);
}